// Round 6
// baseline (625.243 us; speedup 1.0000x reference)
//
#include <hip/hip_runtime.h>

#define DIMS 128
#define RPB 64           // rows per bucket
#define CAP 3072         // edge capacity per bucket (avg 2047, ~23 sigma margin)
#define NBK_MAX 1600
#define NBINS 1024       // 64 rows x 16 column bands (col>>13 in [0,12])

typedef _Float16 half_t;
typedef _Float16 half2_t __attribute__((ext_vector_type(2)));

static __device__ __forceinline__ unsigned halfbits(float v) {
    half_t h = (half_t)v;
    unsigned short us;
    __builtin_memcpy(&us, &h, 2);
    return (unsigned)us;
}

// fp32 -> fp16 convert (x -> xh), 2 elems/thread
__global__ void cvt_kernel(const float* __restrict__ src, half_t* __restrict__ dst, int n2) {
    int i = blockIdx.x * blockDim.x + threadIdx.x;
    if (i >= n2) return;
    float2 v = reinterpret_cast<const float2*>(src)[i];
    half2_t h;
    h.x = (half_t)v.x;
    h.y = (half_t)v.y;
    reinterpret_cast<half2_t*>(&dst[0])[i] = h;
}

// Binning pass: append (rl<<26 | col<<8, half2{v,v}) to bucket row>>6.
// col<<8 IS the byte offset into the fp16 table (col*128*2) -> SpMM needs no
// shift. 4 edges/thread/iter via int4 loads.
__global__ __launch_bounds__(256) void binA_kernel(
    const int* __restrict__ row, const int* __restrict__ col,
    const float* __restrict__ val, int E, int nbk,
    int* __restrict__ fill, int2* __restrict__ staged) {
    __shared__ int cnt[NBK_MAX];
    __shared__ int base[NBK_MAX];
    const int t = threadIdx.x;
    const int tile0 = blockIdx.x * 8192;
    for (int j = t; j < nbk; j += 256) cnt[j] = 0;
    __syncthreads();
    for (int k = 0; k < 8; ++k) {
        int e = tile0 + (k * 256 + t) * 4;
        if (e + 3 < E) {
            int4 r4 = *reinterpret_cast<const int4*>(&row[e]);
            atomicAdd(&cnt[r4.x >> 6], 1);
            atomicAdd(&cnt[r4.y >> 6], 1);
            atomicAdd(&cnt[r4.z >> 6], 1);
            atomicAdd(&cnt[r4.w >> 6], 1);
        } else {
            for (int j = e; j < E; ++j) atomicAdd(&cnt[row[j] >> 6], 1);
        }
    }
    __syncthreads();
    for (int j = t; j < nbk; j += 256) {
        int c = cnt[j];
        base[j] = c ? atomicAdd(&fill[j], c) : 0;
        cnt[j] = 0;
    }
    __syncthreads();
    for (int k = 0; k < 8; ++k) {
        int e = tile0 + (k * 256 + t) * 4;
        int n = (e + 3 < E) ? 4 : max(0, E - e);
        if (n == 4) {
            int4 r4 = *reinterpret_cast<const int4*>(&row[e]);
            int4 c4 = *reinterpret_cast<const int4*>(&col[e]);
            float4 v4 = *reinterpret_cast<const float4*>(&val[e]);
            int rr[4] = {r4.x, r4.y, r4.z, r4.w};
            int cc[4] = {c4.x, c4.y, c4.z, c4.w};
            float vv[4] = {v4.x, v4.y, v4.z, v4.w};
#pragma unroll
            for (int j = 0; j < 4; ++j) {
                int b = rr[j] >> 6;
                int p = base[b] + atomicAdd(&cnt[b], 1);
                if (p < CAP) {
                    unsigned hb = halfbits(vv[j]);
                    int2 pk;
                    pk.x = (int)(((unsigned)(rr[j] & 63) << 26) | ((unsigned)cc[j] << 8));
                    pk.y = (int)((hb << 16) | hb);
                    staged[(size_t)b * CAP + p] = pk;
                }
            }
        } else {
            for (int j = e; j < e + n; ++j) {
                int r = row[j];
                int b = r >> 6;
                int p = base[b] + atomicAdd(&cnt[b], 1);
                if (p < CAP) {
                    unsigned hb = halfbits(val[j]);
                    int2 pk;
                    pk.x = (int)(((unsigned)(r & 63) << 26) | ((unsigned)col[j] << 8));
                    pk.y = (int)((hb << 16) | hb);
                    staged[(size_t)b * CAP + p] = pk;
                }
            }
        }
    }
}

// In-LDS counting sort of one bucket by (row_local, col band): key =
// (rl<<4)|band, band = col>>13 in [0,12]. Emits per-row (start<<16 | end).
__global__ __launch_bounds__(512) void sort_bucket(
    const int* __restrict__ fill, int2* __restrict__ staged,
    int* __restrict__ rowinfo, int N) {
    __shared__ int2 buf[CAP];    // 24 KB
    __shared__ int2 outb[CAP];   // 24 KB
    __shared__ int cur[NBINS];   // 4 KB
    __shared__ int wsum[8];
    const int b = blockIdx.x;
    const int t = threadIdx.x;
    const int w = t >> 6, lane = t & 63;
    const int cnt = min(fill[b], CAP);
    int2* gb = staged + (size_t)b * CAP;

    cur[2 * t] = 0;
    cur[2 * t + 1] = 0;
    for (int i = t; i < cnt; i += 512) buf[i] = gb[i];
    __syncthreads();
    for (int i = t; i < cnt; i += 512) {
        unsigned k = (unsigned)buf[i].x;
        int key = (int)((k >> 26) << 4) | (int)((k >> 21) & 0xF);
        atomicAdd(&cur[key], 1);
    }
    __syncthreads();
    int h0 = cur[2 * t], h1 = cur[2 * t + 1];
    int s = h0 + h1;
    int v = s;
    for (int d = 1; d < 64; d <<= 1) {
        int u = __shfl_up(v, d, 64);
        if (lane >= d) v += u;
    }
    if (lane == 63) wsum[w] = v;
    __syncthreads();
    if (t < 8) {
        int ws = wsum[t];
        int vv = ws;
        for (int d = 1; d < 8; d <<= 1) {
            int u = __shfl_up(vv, d, 64);
            if (t >= d) vv += u;
        }
        wsum[t] = vv - ws;
    }
    __syncthreads();
    int excl = wsum[w] + (v - s);
    cur[2 * t] = excl;
    cur[2 * t + 1] = excl + h0;
    __syncthreads();
    if (t < RPB) {
        int start = cur[t * 16];
        int end = (t == RPB - 1) ? cnt : cur[t * 16 + 16];
        int r = b * RPB + t;
        if (r < N) rowinfo[r] = (start << 16) | end;
    }
    __syncthreads();
    for (int i = t; i < cnt; i += 512) {
        int2 pk = buf[i];
        unsigned k = (unsigned)pk.x;
        int key = (int)((k >> 26) << 4) | (int)((k >> 21) & 0xF);
        int p = atomicAdd(&cur[key], 1);
        outb[p] = pk;
    }
    __syncthreads();
    for (int i = t; i < cnt; i += 512) gb[i] = outb[i];
}

// ---------------- SpMM: one wave per row, half2/lane, v_pk_fma_f16 ----------
// MODE 0: emb_out = A*xh;   acc_h = xh + A*xh        (layer 1)
// MODE 1: emb_out = A*e1;   acc_h += A*e1            (layer 2, emb_out==xh reused)
// MODE 2: out = (acc_h + A*e2) * 0.25  (fp32 final)  (layer 3)
template <int MODE>
__global__ __launch_bounds__(256) void spmm_kernel(
    const half_t* __restrict__ emb_in, const int* __restrict__ rowinfo,
    const int2* __restrict__ staged, int N,
    half_t* __restrict__ emb_out, half_t* __restrict__ acc_h,
    float* __restrict__ out) {
    int r = (blockIdx.x * blockDim.x + threadIdx.x) >> 6;  // wave id = row
    int lane = threadIdx.x & 63;
    if (r >= N) return;
    int info = rowinfo[r];
    int start = info >> 16;
    int end = info & 0xFFFF;
    const long long* eb =
        reinterpret_cast<const long long*>(staged + (size_t)(r >> 6) * CAP);
    const char* tbl = reinterpret_cast<const char*>(emb_in);
    const unsigned lane4 = (unsigned)lane << 2;

    half2_t acc[8];
#pragma unroll
    for (int k = 0; k < 8; ++k) acc[k] = (half2_t)0;

    int e = start;
    for (; e + 7 < end; e += 8) {  // 8 gathers in flight
        long long raw[8];
#pragma unroll
        for (int k = 0; k < 8; ++k) raw[k] = __builtin_nontemporal_load(&eb[e + k]);
        half2_t tv[8];
#pragma unroll
        for (int k = 0; k < 8; ++k) {
            unsigned voff = (((unsigned)(unsigned int)raw[k]) & 0x03FFFF00u) + lane4;
            tv[k] = *reinterpret_cast<const half2_t*>(tbl + voff);
        }
#pragma unroll
        for (int k = 0; k < 8; ++k) {
            unsigned pv = (unsigned)((unsigned long long)raw[k] >> 32);
            half2_t vv = __builtin_bit_cast(half2_t, pv);
            acc[k] = tv[k] * vv + acc[k];  // v_pk_fma_f16
        }
    }
    for (; e < end; ++e) {
        long long raw = __builtin_nontemporal_load(&eb[e]);
        unsigned voff = (((unsigned)(unsigned int)raw) & 0x03FFFF00u) + lane4;
        half2_t tvs = *reinterpret_cast<const half2_t*>(tbl + voff);
        unsigned pv = (unsigned)((unsigned long long)raw >> 32);
        half2_t vv = __builtin_bit_cast(half2_t, pv);
        acc[0] = tvs * vv + acc[0];
    }
    half2_t a01 = acc[0] + acc[1], a23 = acc[2] + acc[3];
    half2_t a45 = acc[4] + acc[5], a67 = acc[6] + acc[7];
    half2_t a = (a01 + a23) + (a45 + a67);

    size_t o = (size_t)r * DIMS + 2 * lane;
    if (MODE == 0 || MODE == 1) {
        *reinterpret_cast<half2_t*>(&emb_out[o]) = a;
    }
    if (MODE == 0) {
        half2_t xv = *reinterpret_cast<const half2_t*>(&emb_in[o]);
        *reinterpret_cast<half2_t*>(&acc_h[o]) = xv + a;
    } else if (MODE == 1) {
        half2_t cv = *reinterpret_cast<half2_t*>(&acc_h[o]);
        *reinterpret_cast<half2_t*>(&acc_h[o]) = cv + a;
    } else {
        half2_t cv = *reinterpret_cast<half2_t*>(&acc_h[o]);
        *reinterpret_cast<float2*>(&out[o]) =
            make_float2(((float)cv.x + (float)a.x) * 0.25f,
                        ((float)cv.y + (float)a.y) * 0.25f);
    }
}

// ---------------- launch ----------------

extern "C" void kernel_launch(void* const* d_in, const int* in_sizes, int n_in,
                              void* d_out, int out_size, void* d_ws, size_t ws_size,
                              hipStream_t stream) {
    const float* x = (const float*)d_in[0];
    const int* erow = (const int*)d_in[1];
    const int* ecol = (const int*)d_in[2];
    const float* eval = (const float*)d_in[3];
    const int N = in_sizes[0] / DIMS;  // 100000
    const int E = in_sizes[1];         // 3200000
    float* out = (float*)d_out;
    const int nbk = (N + RPB - 1) / RPB;  // 1563

    char* ws = (char*)d_ws;
    size_t off = 0;
    auto carve = [&](size_t bytes) {
        void* p = ws + off;
        off = (off + bytes + 255) & ~(size_t)255;
        return p;
    };
    half_t* xh = (half_t*)carve((size_t)N * DIMS * sizeof(half_t));  // also layer-2 output
    half_t* embB1 = (half_t*)carve((size_t)N * DIMS * sizeof(half_t));
    half_t* acc_h = (half_t*)carve((size_t)N * DIMS * sizeof(half_t));
    int2* staged = (int2*)carve((size_t)nbk * CAP * sizeof(int2));
    int* fill = (int*)carve((size_t)nbk * sizeof(int));
    int* rowinfo = (int*)carve((size_t)N * sizeof(int));
    (void)ws_size;

    hipMemsetAsync(fill, 0, (size_t)nbk * sizeof(int), stream);
    const int n2 = N * DIMS / 2;
    cvt_kernel<<<(n2 + 255) / 256, 256, 0, stream>>>(x, xh, n2);
    binA_kernel<<<(E + 8191) / 8192, 256, 0, stream>>>(erow, ecol, eval, E, nbk, fill, staged);
    sort_bucket<<<nbk, 512, 0, stream>>>(fill, staged, rowinfo, N);

    const int spmm_blocks = (N + 3) / 4;  // 4 waves (rows) per 256-thread block
    spmm_kernel<0><<<spmm_blocks, 256, 0, stream>>>(xh, rowinfo, staged, N, embB1, acc_h, out);
    spmm_kernel<1><<<spmm_blocks, 256, 0, stream>>>(embB1, rowinfo, staged, N, xh, acc_h, out);
    spmm_kernel<2><<<spmm_blocks, 256, 0, stream>>>(xh, rowinfo, staged, N, embB1, acc_h, out);
}

// Round 7
// 541.683 us; speedup vs baseline: 1.1543x; 1.1543x over previous
//
#include <hip/hip_runtime.h>

#define DIMS 128
#define RPB 64           // rows per bucket
#define CAP 3072         // edge capacity per bucket (avg 2047, ~23 sigma margin)
#define NBK_MAX 1600
#define NBINS 1024       // 64 rows x 16 column bands (col band = col>>13 in [0,12])

typedef _Float16 half_t;
typedef _Float16 half2_t __attribute__((ext_vector_type(2)));

static __device__ __forceinline__ unsigned halfbits(float v) {
    half_t h = (half_t)v;
    unsigned short us;
    __builtin_memcpy(&us, &h, 2);
    return (unsigned)us;
}

// fp32 -> fp16 convert (x -> xh), 2 elems/thread
__global__ void cvt_kernel(const float* __restrict__ src, half_t* __restrict__ dst, int n2) {
    int i = blockIdx.x * blockDim.x + threadIdx.x;
    if (i >= n2) return;
    float2 v = reinterpret_cast<const float2*>(src)[i];
    half2_t h;
    h.x = (half_t)v.x;
    h.y = (half_t)v.y;
    reinterpret_cast<half2_t*>(&dst[0])[i] = h;
}

// Binning pass: append (rl<<26 | col<<8, half2{v,v}) to bucket row>>6.
// col<<8 IS the byte offset into the fp16 table (col*128*2).
__global__ __launch_bounds__(256) void binA_kernel(
    const int* __restrict__ row, const int* __restrict__ col,
    const float* __restrict__ val, int E, int nbk,
    int* __restrict__ fill, int2* __restrict__ staged) {
    __shared__ int cnt[NBK_MAX];
    __shared__ int base[NBK_MAX];
    const int t = threadIdx.x;
    const int tile0 = blockIdx.x * 8192;
    for (int j = t; j < nbk; j += 256) cnt[j] = 0;
    __syncthreads();
    for (int k = 0; k < 8; ++k) {
        int e = tile0 + (k * 256 + t) * 4;
        if (e + 3 < E) {
            int4 r4 = *reinterpret_cast<const int4*>(&row[e]);
            atomicAdd(&cnt[r4.x >> 6], 1);
            atomicAdd(&cnt[r4.y >> 6], 1);
            atomicAdd(&cnt[r4.z >> 6], 1);
            atomicAdd(&cnt[r4.w >> 6], 1);
        } else {
            for (int j = e; j < E; ++j) atomicAdd(&cnt[row[j] >> 6], 1);
        }
    }
    __syncthreads();
    for (int j = t; j < nbk; j += 256) {
        int c = cnt[j];
        base[j] = c ? atomicAdd(&fill[j], c) : 0;
        cnt[j] = 0;
    }
    __syncthreads();
    for (int k = 0; k < 8; ++k) {
        int e = tile0 + (k * 256 + t) * 4;
        int n = (e + 3 < E) ? 4 : max(0, E - e);
        if (n == 4) {
            int4 r4 = *reinterpret_cast<const int4*>(&row[e]);
            int4 c4 = *reinterpret_cast<const int4*>(&col[e]);
            float4 v4 = *reinterpret_cast<const float4*>(&val[e]);
            int rr[4] = {r4.x, r4.y, r4.z, r4.w};
            int cc[4] = {c4.x, c4.y, c4.z, c4.w};
            float vv[4] = {v4.x, v4.y, v4.z, v4.w};
#pragma unroll
            for (int j = 0; j < 4; ++j) {
                int b = rr[j] >> 6;
                int p = base[b] + atomicAdd(&cnt[b], 1);
                if (p < CAP) {
                    unsigned hb = halfbits(vv[j]);
                    int2 pk;
                    pk.x = (int)(((unsigned)(rr[j] & 63) << 26) | ((unsigned)cc[j] << 8));
                    pk.y = (int)((hb << 16) | hb);
                    staged[(size_t)b * CAP + p] = pk;
                }
            }
        } else {
            for (int j = e; j < e + n; ++j) {
                int r = row[j];
                int b = r >> 6;
                int p = base[b] + atomicAdd(&cnt[b], 1);
                if (p < CAP) {
                    unsigned hb = halfbits(val[j]);
                    int2 pk;
                    pk.x = (int)(((unsigned)(r & 63) << 26) | ((unsigned)col[j] << 8));
                    pk.y = (int)((hb << 16) | hb);
                    staged[(size_t)b * CAP + p] = pk;
                }
            }
        }
    }
}

// In-LDS counting sort of one bucket by (row_local, col band): key =
// (rl<<4)|band. Emits per-row (start<<16 | end) relative to bucket base.
__global__ __launch_bounds__(512) void sort_bucket(
    const int* __restrict__ fill, int2* __restrict__ staged,
    int* __restrict__ rowinfo, int N) {
    __shared__ int2 buf[CAP];    // 24 KB
    __shared__ int2 outb[CAP];   // 24 KB
    __shared__ int cur[NBINS];   // 4 KB
    __shared__ int wsum[8];
    const int b = blockIdx.x;
    const int t = threadIdx.x;
    const int w = t >> 6, lane = t & 63;
    const int cnt = min(fill[b], CAP);
    int2* gb = staged + (size_t)b * CAP;

    cur[2 * t] = 0;
    cur[2 * t + 1] = 0;
    for (int i = t; i < cnt; i += 512) buf[i] = gb[i];
    __syncthreads();
    for (int i = t; i < cnt; i += 512) {
        unsigned k = (unsigned)buf[i].x;
        int key = (int)((k >> 26) << 4) | (int)((k >> 21) & 0xF);
        atomicAdd(&cur[key], 1);
    }
    __syncthreads();
    int h0 = cur[2 * t], h1 = cur[2 * t + 1];
    int s = h0 + h1;
    int v = s;
    for (int d = 1; d < 64; d <<= 1) {
        int u = __shfl_up(v, d, 64);
        if (lane >= d) v += u;
    }
    if (lane == 63) wsum[w] = v;
    __syncthreads();
    if (t < 8) {
        int ws = wsum[t];
        int vv = ws;
        for (int d = 1; d < 8; d <<= 1) {
            int u = __shfl_up(vv, d, 64);
            if (t >= d) vv += u;
        }
        wsum[t] = vv - ws;
    }
    __syncthreads();
    int excl = wsum[w] + (v - s);
    cur[2 * t] = excl;
    cur[2 * t + 1] = excl + h0;
    __syncthreads();
    if (t < RPB) {
        int start = cur[t * 16];
        int end = (t == RPB - 1) ? cnt : cur[t * 16 + 16];
        int r = b * RPB + t;
        if (r < N) rowinfo[r] = (start << 16) | end;
    }
    __syncthreads();
    for (int i = t; i < cnt; i += 512) {
        int2 pk = buf[i];
        unsigned k = (unsigned)pk.x;
        int key = (int)((k >> 26) << 4) | (int)((k >> 21) & 0xF);
        int p = atomicAdd(&cur[key], 1);
        outb[p] = pk;
    }
    __syncthreads();
    for (int i = t; i < cnt; i += 512) gb[i] = outb[i];
}

// ---------------- SpMM: one wave per row --------------------------------
// Edge list loaded ONCE per row, coalesced (lane i holds edge start+i), then
// broadcast per-edge via __shfl -> the per-batch dependent chain is 1 miss
// deep (gather only) instead of 2 (edge load -> gather).
// MODE 0: emb_out = A*xh;   acc_h = xh + A*xh        (layer 1)
// MODE 1: emb_out = A*e1;   acc_h += A*e1            (layer 2, emb_out==xh reused)
// MODE 2: out = (acc_h + A*e2) * 0.25  (fp32 final)  (layer 3)
template <int MODE>
__global__ __launch_bounds__(256) void spmm_kernel(
    const half_t* __restrict__ emb_in, const int* __restrict__ rowinfo,
    const int2* __restrict__ staged, int N,
    half_t* __restrict__ emb_out, half_t* __restrict__ acc_h,
    float* __restrict__ out) {
    int r = (blockIdx.x * blockDim.x + threadIdx.x) >> 6;  // wave id = row
    int lane = threadIdx.x & 63;
    if (r >= N) return;
    int info = rowinfo[r];
    int start = info >> 16;
    int end = info & 0xFFFF;
    const int2* eb = staged + (size_t)(r >> 6) * CAP;
    const char* tbl = reinterpret_cast<const char*>(emb_in);
    const unsigned lane4 = (unsigned)lane << 2;

    half2_t acc[8];
#pragma unroll
    for (int k = 0; k < 8; ++k) acc[k] = (half2_t)0;

    for (int base = start; base < end; base += 64) {
        const int cnt = min(64, end - base);
        // one coalesced load: lane i holds edge base+i
        int2 myE = make_int2(0, 0);
        if (base + lane < end) myE = eb[base + lane];

        int k = 0;
        for (; k + 7 < cnt; k += 8) {
            int ex[8], ey[8];
#pragma unroll
            for (int j = 0; j < 8; ++j) {
                ex[j] = __shfl(myE.x, k + j, 64);
                ey[j] = __shfl(myE.y, k + j, 64);
            }
            half2_t tv[8];
#pragma unroll
            for (int j = 0; j < 8; ++j) {
                unsigned voff = (((unsigned)ex[j]) & 0x03FFFF00u) + lane4;
                tv[j] = *reinterpret_cast<const half2_t*>(tbl + voff);
            }
#pragma unroll
            for (int j = 0; j < 8; ++j) {
                half2_t vv = __builtin_bit_cast(half2_t, ey[j]);
                acc[j] = tv[j] * vv + acc[j];  // v_pk_fma_f16
            }
        }
        for (; k < cnt; ++k) {
            int ex = __shfl(myE.x, k, 64);
            int ey = __shfl(myE.y, k, 64);
            unsigned voff = (((unsigned)ex) & 0x03FFFF00u) + lane4;
            half2_t tvs = *reinterpret_cast<const half2_t*>(tbl + voff);
            half2_t vv = __builtin_bit_cast(half2_t, ey);
            acc[0] = tvs * vv + acc[0];
        }
    }
    half2_t a01 = acc[0] + acc[1], a23 = acc[2] + acc[3];
    half2_t a45 = acc[4] + acc[5], a67 = acc[6] + acc[7];
    half2_t a = (a01 + a23) + (a45 + a67);

    size_t o = (size_t)r * DIMS + 2 * lane;
    if (MODE == 0 || MODE == 1) {
        *reinterpret_cast<half2_t*>(&emb_out[o]) = a;
    }
    if (MODE == 0) {
        half2_t xv = *reinterpret_cast<const half2_t*>(&emb_in[o]);
        *reinterpret_cast<half2_t*>(&acc_h[o]) = xv + a;
    } else if (MODE == 1) {
        half2_t cv = *reinterpret_cast<half2_t*>(&acc_h[o]);
        *reinterpret_cast<half2_t*>(&acc_h[o]) = cv + a;
    } else {
        half2_t cv = *reinterpret_cast<half2_t*>(&acc_h[o]);
        *reinterpret_cast<float2*>(&out[o]) =
            make_float2(((float)cv.x + (float)a.x) * 0.25f,
                        ((float)cv.y + (float)a.y) * 0.25f);
    }
}

// ---------------- launch ----------------

extern "C" void kernel_launch(void* const* d_in, const int* in_sizes, int n_in,
                              void* d_out, int out_size, void* d_ws, size_t ws_size,
                              hipStream_t stream) {
    const float* x = (const float*)d_in[0];
    const int* erow = (const int*)d_in[1];
    const int* ecol = (const int*)d_in[2];
    const float* eval = (const float*)d_in[3];
    const int N = in_sizes[0] / DIMS;  // 100000
    const int E = in_sizes[1];         // 3200000
    float* out = (float*)d_out;
    const int nbk = (N + RPB - 1) / RPB;  // 1563

    char* ws = (char*)d_ws;
    size_t off = 0;
    auto carve = [&](size_t bytes) {
        void* p = ws + off;
        off = (off + bytes + 255) & ~(size_t)255;
        return p;
    };
    half_t* xh = (half_t*)carve((size_t)N * DIMS * sizeof(half_t));  // also layer-2 output
    half_t* embB1 = (half_t*)carve((size_t)N * DIMS * sizeof(half_t));
    half_t* acc_h = (half_t*)carve((size_t)N * DIMS * sizeof(half_t));
    int2* staged = (int2*)carve((size_t)nbk * CAP * sizeof(int2));
    int* fill = (int*)carve((size_t)nbk * sizeof(int));
    int* rowinfo = (int*)carve((size_t)N * sizeof(int));
    (void)ws_size;

    hipMemsetAsync(fill, 0, (size_t)nbk * sizeof(int), stream);
    const int n2 = N * DIMS / 2;
    cvt_kernel<<<(n2 + 255) / 256, 256, 0, stream>>>(x, xh, n2);
    binA_kernel<<<(E + 8191) / 8192, 256, 0, stream>>>(erow, ecol, eval, E, nbk, fill, staged);
    sort_bucket<<<nbk, 512, 0, stream>>>(fill, staged, rowinfo, N);

    const int spmm_blocks = (N + 3) / 4;  // 4 waves (rows) per 256-thread block
    spmm_kernel<0><<<spmm_blocks, 256, 0, stream>>>(xh, rowinfo, staged, N, embB1, acc_h, out);
    spmm_kernel<1><<<spmm_blocks, 256, 0, stream>>>(embB1, rowinfo, staged, N, xh, acc_h, out);
    spmm_kernel<2><<<spmm_blocks, 256, 0, stream>>>(xh, rowinfo, staged, N, embB1, acc_h, out);
}